// Round 1
// baseline (646.262 us; speedup 1.0000x reference)
//
#include <hip/hip_runtime.h>
#include <hip/hip_bf16.h>

// Problem constants (B=64, T=1000, IN=OUT=512)
//   outputs  zs     [64,1000,512]        -> d_out[0 .. 32768000)
//   states   v_full [64,1001,512]        -> d_out[32768000 .. 65568768)
//   states   z_full [64,1001,512]        -> d_out[65568768 .. 98369536)
#define SV_OFF 32768000
#define SZ_OFF 65568768

typedef __attribute__((ext_vector_type(8))) short bf16x8;
typedef __attribute__((ext_vector_type(4))) float f32x4;

__device__ __forceinline__ unsigned short f2bf(float f) {
  union { float f; unsigned u; } x; x.f = f;
  unsigned r = x.u + 0x7fffu + ((x.u >> 16) & 1u);  // RNE
  return (unsigned short)(r >> 16);
}

__device__ __forceinline__ void gl_lds16(const void* g, void* l) {
  __builtin_amdgcn_global_load_lds(
      (const __attribute__((address_space(1))) unsigned int*)g,
      (__attribute__((address_space(3))) unsigned int*)l, 16, 0, 0);
}

// ---------------------------------------------------------------- prep
// W (512x512 f32) -> bf16; R -> R^T (for coalesced fixup reads); zero flags.
__global__ __launch_bounds__(256) void prep(const float* __restrict__ W,
                                            const float* __restrict__ R,
                                            unsigned short* __restrict__ Wb,
                                            float* __restrict__ RT,
                                            int* __restrict__ flags) {
  const int idx = blockIdx.x * 256 + threadIdx.x;
  if (idx < 512 * 512) {
    Wb[idx] = f2bf(W[idx]);
    const int j = idx >> 9;       // RT[j][o] = R[o][j]
    const int o = idx & 511;
    RT[idx] = R[o * 512 + j];
  }
  if (idx < 64) flags[idx] = 0;
}

// ---------------------------------------------------------------- GEMM
// cur[m][n] = sum_k x[m][k] * W[n][k] + bias[n], bf16 MFMA 16x16x32.
// 128x128 tile, BK=32, 256 threads (4 waves in 2x2 quadrants).
__global__ __launch_bounds__(256, 2) void gemm_cur(
    const float* __restrict__ A,            // x [64000,512] f32
    const unsigned short* __restrict__ Wb,  // [512,512] bf16
    const float* __restrict__ bias,
    float* __restrict__ C) {                // cur [64000,512] f32
  __shared__ unsigned short As[128][40];    // +8 pad: spreads banks for b128 reads
  __shared__ unsigned short Bs[128][32];    // unpadded: global_load_lds layout
  const int tid = threadIdx.x;
  const int bn = blockIdx.x * 128;          // n fastest -> A-tile L2 reuse
  const int bm = blockIdx.y * 128;
  const int wave = tid >> 6;
  const int lane = tid & 63;
  const int lr = lane & 15;
  const int lq = lane >> 4;
  const int mh = (wave & 1) * 64;
  const int nh = (wave >> 1) * 64;

  f32x4 acc[4][4] = {};

  const int arow = tid >> 3;                // 0..31
  const int acol = (tid & 7) * 4;           // 0..28
  const int ldsoff0 = tid * 16;

  for (int kk = 0; kk < 16; ++kk) {
    const int k0 = kk * 32;
    __syncthreads();
    // stage A: fp32 load -> bf16 cvt -> LDS
#pragma unroll
    for (int p = 0; p < 4; ++p) {
      const int r = arow + p * 32;
      const float4 a4 = *(const float4*)(A + (size_t)(bm + r) * 512 + k0 + acol);
      ushort4 h;
      h.x = f2bf(a4.x); h.y = f2bf(a4.y); h.z = f2bf(a4.z); h.w = f2bf(a4.w);
      *(ushort4*)(&As[r][acol]) = h;
    }
    // stage B: async 16B direct-to-LDS (wave-uniform base + lane*16)
#pragma unroll
    for (int q = 0; q < 2; ++q) {
      const int lo = q * 4096 + ldsoff0;
      const int row = lo >> 6;              // 64 B per Bs row
      const int kb = lo & 63;
      gl_lds16((const char*)Wb + (size_t)(bn + row) * 1024 + (size_t)k0 * 2 + kb,
               (char*)(&Bs[0][0]) + lo);
    }
    __syncthreads();
    bf16x8 af[4], bfr[4];
#pragma unroll
    for (int i = 0; i < 4; ++i)
      af[i] = *(const bf16x8*)(&As[mh + i * 16 + lr][lq * 8]);
#pragma unroll
    for (int j = 0; j < 4; ++j)
      bfr[j] = *(const bf16x8*)(&Bs[nh + j * 16 + lr][lq * 8]);
#pragma unroll
    for (int i = 0; i < 4; ++i)
#pragma unroll
      for (int j = 0; j < 4; ++j)
        acc[i][j] = __builtin_amdgcn_mfma_f32_16x16x32_bf16(af[i], bfr[j], acc[i][j], 0, 0, 0);
  }
  // epilogue: C/D layout col=lane&15, row=(lane>>4)*4+reg
#pragma unroll
  for (int j = 0; j < 4; ++j) {
    const int col = bn + nh + j * 16 + lr;
    const float bv = bias[col];
#pragma unroll
    for (int i = 0; i < 4; ++i) {
      const int r0 = bm + mh + i * 16 + lq * 4;
#pragma unroll
      for (int r = 0; r < 4; ++r)
        C[(size_t)(r0 + r) * 512 + col] = acc[i][j][r] + bv;
    }
  }
}

// ---------------------------------------------------------------- speculative scan
// One thread per (b,o). Assumes no neuron in the batch spiked (recurrent term = 0);
// own reset handled exactly. Sets flags[b] if ANY spike -> fixup kernel redoes batch.
__global__ __launch_bounds__(64) void scan_spec(const float* __restrict__ cur,
                                                const float* __restrict__ decay,
                                                float* __restrict__ out,
                                                int* __restrict__ flags) {
  const int b = blockIdx.x >> 3;
  const int o = ((blockIdx.x & 7) << 6) + threadIdx.x;
  const float d = decay[o];
  const float om = 1.0f - d;
  float v = 0.f, z = 0.f;
  int fl = 0;
  const size_t ci = (size_t)b * 512000 + o;    // cur / outputs index base
  const size_t svb = (size_t)b * 512512 + o;   // states index base (T+1 rows)
  float* __restrict__ sv = out + SV_OFF;
  float* __restrict__ sz = out + SZ_OFF;
  sv[svb] = 0.f;                                // t=0 state rows
  sz[svb] = 0.f;
  float nb[8];
#pragma unroll
  for (int u = 0; u < 8; ++u) nb[u] = cur[ci + (size_t)u * 512];
  for (int t = 0; t < 1000; t += 8) {
    float cb[8];
#pragma unroll
    for (int u = 0; u < 8; ++u) cb[u] = nb[u];
    if (t + 8 < 1000) {
      const size_t p = ci + (size_t)(t + 8) * 512;
#pragma unroll
      for (int u = 0; u < 8; ++u) nb[u] = cur[p + (size_t)u * 512];
    }
#pragma unroll
    for (int u = 0; u < 8; ++u) {
      v = d * (v * (1.f - z)) + om * cb[u];
      z = (v >= 1.0f) ? 1.0f : 0.0f;
      fl |= (v >= 1.0f);
      const size_t row = (size_t)(t + u) * 512;
      out[ci + row] = z;
      sv[svb + row + 512] = v;
      sz[svb + row + 512] = z;
    }
  }
  if (fl) atomicOr(flags + b, 1);
}

// ---------------------------------------------------------------- fixup (rare path)
// Full sequential recompute with recurrent coupling for batches that spiked.
__global__ __launch_bounds__(512) void scan_fix(const float* __restrict__ cur,
                                                const float* __restrict__ decay,
                                                const float* __restrict__ RT,
                                                float* __restrict__ out,
                                                const int* __restrict__ flags) {
  const int b = blockIdx.x;
  if (flags[b] == 0) return;
  const int o = threadIdx.x;  // 512 threads = 512 neurons
  __shared__ int cnt;
  __shared__ int list[512];
  const float d = decay[o];
  const float om = 1.f - d;
  float v = 0.f, z = 0.f;
  const size_t ci = (size_t)b * 512000 + o;
  const size_t svb = (size_t)b * 512512 + o;
  float* __restrict__ sv = out + SV_OFF;
  float* __restrict__ sz = out + SZ_OFF;
  sv[svb] = 0.f;
  sz[svb] = 0.f;
  if (o == 0) cnt = 0;
  __syncthreads();
  for (int t = 0; t < 1000; ++t) {
    float soma = cur[ci + (size_t)t * 512];
    const int n = cnt;  // spikes at t-1
    for (int i = 0; i < n; ++i) soma += RT[(size_t)list[i] * 512 + o];
    v = d * (v * (1.f - z)) + om * soma;
    z = (v >= 1.0f) ? 1.0f : 0.0f;
    out[ci + (size_t)t * 512] = z;
    sv[svb + (size_t)(t + 1) * 512] = v;
    sz[svb + (size_t)(t + 1) * 512] = z;
    __syncthreads();                 // everyone done reading cnt/list
    if (o == 0) cnt = 0;
    __syncthreads();
    if (z != 0.f) { const int p = atomicAdd(&cnt, 1); list[p] = o; }
    __syncthreads();
  }
}

extern "C" void kernel_launch(void* const* d_in, const int* in_sizes, int n_in,
                              void* d_out, int out_size, void* d_ws, size_t ws_size,
                              hipStream_t stream) {
  (void)in_sizes; (void)n_in; (void)out_size; (void)ws_size;
  const float* x     = (const float*)d_in[0];  // [64,1000,512]
  const float* W     = (const float*)d_in[1];  // [512,512]
  const float* bias  = (const float*)d_in[2];  // [512]
  const float* R     = (const float*)d_in[3];  // [512,512]
  const float* decay = (const float*)d_in[4];  // [512]
  float* out = (float*)d_out;

  char* ws = (char*)d_ws;
  float* cur          = (float*)ws;                      // 131,072,000 B
  unsigned short* Wb  = (unsigned short*)(ws + 131072000); //    524,288 B
  float* RT           = (float*)(ws + 131596288);        //  1,048,576 B
  int* flags          = (int*)(ws + 132644864);          //        256 B

  prep<<<1024, 256, 0, stream>>>(W, R, Wb, RT, flags);
  gemm_cur<<<dim3(4, 500), 256, 0, stream>>>(x, Wb, bias, cur);
  scan_spec<<<512, 64, 0, stream>>>(cur, decay, out, flags);
  scan_fix<<<64, 512, 0, stream>>>(cur, decay, RT, out, flags);
}

// Round 2
// 618.649 us; speedup vs baseline: 1.0446x; 1.0446x over previous
//
#include <hip/hip_runtime.h>
#include <hip/hip_bf16.h>

// Problem constants (B=64, T=1000, IN=OUT=512)
//   outputs  zs     [64,1000,512]        -> d_out[0 .. 32768000)
//   states   v_full [64,1001,512]        -> d_out[32768000 .. 65568768)
//   states   z_full [64,1001,512]        -> d_out[65568768 .. 98369536)
#define SV_OFF 32768000
#define SZ_OFF 65568768
#define TC 125   // timesteps per chunk
#define NC 8     // chunks (TC*NC = 1000)

typedef __attribute__((ext_vector_type(8))) short bf16x8;
typedef __attribute__((ext_vector_type(4))) float f32x4;

__device__ __forceinline__ unsigned short f2bf(float f) {
  union { float f; unsigned u; } x; x.f = f;
  unsigned r = x.u + 0x7fffu + ((x.u >> 16) & 1u);  // RNE
  return (unsigned short)(r >> 16);
}

__device__ __forceinline__ void gl_lds16(const void* g, void* l) {
  __builtin_amdgcn_global_load_lds(
      (const __attribute__((address_space(1))) unsigned int*)g,
      (__attribute__((address_space(3))) unsigned int*)l, 16, 0, 0);
}

// ---------------------------------------------------------------- prep
__global__ __launch_bounds__(256) void prep(const float* __restrict__ W,
                                            const float* __restrict__ R,
                                            unsigned short* __restrict__ Wb,
                                            float* __restrict__ RT,
                                            int* __restrict__ flags) {
  const int idx = blockIdx.x * 256 + threadIdx.x;
  if (idx < 512 * 512) {
    Wb[idx] = f2bf(W[idx]);
    const int j = idx >> 9;       // RT[j][o] = R[o][j]
    const int o = idx & 511;
    RT[idx] = R[o * 512 + j];
  }
  if (idx < 64) flags[idx] = 0;
}

// ---------------------------------------------------------------- GEMM
// cur[m][n] = sum_k x[m][k] * W[n][k] + bias[n], bf16 MFMA 16x16x32.
__global__ __launch_bounds__(256, 2) void gemm_cur(
    const float* __restrict__ A,            // x [64000,512] f32
    const unsigned short* __restrict__ Wb,  // [512,512] bf16
    const float* __restrict__ bias,
    float* __restrict__ C) {                // cur [64000,512] f32
  __shared__ unsigned short As[128][40];
  __shared__ unsigned short Bs[128][32];
  const int tid = threadIdx.x;
  const int bn = blockIdx.x * 128;
  const int bm = blockIdx.y * 128;
  const int wave = tid >> 6;
  const int lane = tid & 63;
  const int lr = lane & 15;
  const int lq = lane >> 4;
  const int mh = (wave & 1) * 64;
  const int nh = (wave >> 1) * 64;

  f32x4 acc[4][4] = {};

  const int arow = tid >> 3;
  const int acol = (tid & 7) * 4;
  const int ldsoff0 = tid * 16;

  for (int kk = 0; kk < 16; ++kk) {
    const int k0 = kk * 32;
    __syncthreads();
#pragma unroll
    for (int p = 0; p < 4; ++p) {
      const int r = arow + p * 32;
      const float4 a4 = *(const float4*)(A + (size_t)(bm + r) * 512 + k0 + acol);
      ushort4 h;
      h.x = f2bf(a4.x); h.y = f2bf(a4.y); h.z = f2bf(a4.z); h.w = f2bf(a4.w);
      *(ushort4*)(&As[r][acol]) = h;
    }
#pragma unroll
    for (int q = 0; q < 2; ++q) {
      const int lo = q * 4096 + ldsoff0;
      const int row = lo >> 6;
      const int kb = lo & 63;
      gl_lds16((const char*)Wb + (size_t)(bn + row) * 1024 + (size_t)k0 * 2 + kb,
               (char*)(&Bs[0][0]) + lo);
    }
    __syncthreads();
    bf16x8 af[4], bfr[4];
#pragma unroll
    for (int i = 0; i < 4; ++i)
      af[i] = *(const bf16x8*)(&As[mh + i * 16 + lr][lq * 8]);
#pragma unroll
    for (int j = 0; j < 4; ++j)
      bfr[j] = *(const bf16x8*)(&Bs[nh + j * 16 + lr][lq * 8]);
#pragma unroll
    for (int i = 0; i < 4; ++i)
#pragma unroll
      for (int j = 0; j < 4; ++j)
        acc[i][j] = __builtin_amdgcn_mfma_f32_16x16x32_bf16(af[i], bfr[j], acc[i][j], 0, 0, 0);
  }
#pragma unroll
  for (int j = 0; j < 4; ++j) {
    const int col = bn + nh + j * 16 + lr;
    const float bv = bias[col];
#pragma unroll
    for (int i = 0; i < 4; ++i) {
      const int r0 = bm + mh + i * 16 + lq * 4;
#pragma unroll
      for (int r = 0; r < 4; ++r)
        C[(size_t)(r0 + r) * 512 + col] = acc[i][j][r] + bv;
    }
  }
}

// ---------------------------------------------------------------- phase 1
// Chunk-local Horner sums: S[b][j][o] = scan of chunk j from v=0 (exact in-chunk
// fp32 op order of the reference). One thread per (b, j, o): 262144 threads.
__global__ __launch_bounds__(256) void chunk_sums(const float* __restrict__ cur,
                                                  const float* __restrict__ decay,
                                                  float* __restrict__ S) {
  const int gt = blockIdx.x * 256 + threadIdx.x;
  const int o = gt & 511;
  const int j = (gt >> 9) & (NC - 1);
  const int b = gt >> 12;
  const float d = decay[o];
  const float om = 1.0f - d;
  const size_t base = (size_t)b * 512000 + (size_t)(j * TC) * 512 + o;
  float nb[8];
#pragma unroll
  for (int u = 0; u < 8; ++u) nb[u] = cur[base + (size_t)u * 512];
  float s = 0.f;
#pragma unroll 8
  for (int k = 0; k < TC; ++k) {
    const float c = nb[k & 7];
    if (k < TC - 8) nb[k & 7] = cur[base + (size_t)(k + 8) * 512];
    s = d * s + om * c;
  }
  S[gt] = s;
}

// ---------------------------------------------------------------- phase 2
// Chunk-start prefix: Vs[b][j][o] = v at start of chunk j (speculative linear path).
__global__ __launch_bounds__(256) void chunk_prefix(const float* __restrict__ S,
                                                    const float* __restrict__ decay,
                                                    float* __restrict__ Vs) {
  const int gt = blockIdx.x * 256 + threadIdx.x;  // 32768 threads: (b,o)
  const int o = gt & 511;
  const int b = gt >> 9;
  const float d = decay[o];
  const float dTC = powf(d, (float)TC);
  float v = 0.f;
  const int base = (b << 12) + o;  // b*NC*512 + o
#pragma unroll
  for (int j = 0; j < NC; ++j) {
    Vs[base + (j << 9)] = v;
    v = dTC * v + S[base + (j << 9)];
  }
}

// ---------------------------------------------------------------- phase 3
// In-chunk scan from chunk-start v; writes zs, v_full, z_full; flags spikes.
__global__ __launch_bounds__(256) void chunk_scan(const float* __restrict__ cur,
                                                  const float* __restrict__ decay,
                                                  const float* __restrict__ Vs,
                                                  float* __restrict__ out,
                                                  int* __restrict__ flags) {
  const int gt = blockIdx.x * 256 + threadIdx.x;
  const int o = gt & 511;
  const int j = (gt >> 9) & (NC - 1);
  const int b = gt >> 12;
  const float d = decay[o];
  const float om = 1.0f - d;
  const size_t ci = (size_t)b * 512000 + (size_t)(j * TC) * 512 + o;
  const size_t svb = (size_t)b * 512512 + (size_t)(j * TC) * 512 + o;
  float* __restrict__ sv = out + SV_OFF;
  float* __restrict__ sz = out + SZ_OFF;
  if (j == 0) {  // t=0 state rows
    __builtin_nontemporal_store(0.f, &sv[svb]);
    __builtin_nontemporal_store(0.f, &sz[svb]);
  }
  float v = Vs[(b << 12) + (j << 9) + o];
  int fl = 0;
  float nb[8];
#pragma unroll
  for (int u = 0; u < 8; ++u) nb[u] = cur[ci + (size_t)u * 512];
#pragma unroll 8
  for (int k = 0; k < TC; ++k) {
    const float c = nb[k & 7];
    if (k < TC - 8) nb[k & 7] = cur[ci + (size_t)(k + 8) * 512];
    v = d * v + om * c;  // (1-z)=1 multiply is exact in the no-spike path
    const float z = (v >= 1.0f) ? 1.0f : 0.0f;
    fl |= (v >= 1.0f);
    const size_t row = (size_t)k * 512;
    __builtin_nontemporal_store(z, &out[ci + row]);
    __builtin_nontemporal_store(v, &sv[svb + row + 512]);
    __builtin_nontemporal_store(z, &sz[svb + row + 512]);
  }
  if (fl) atomicOr(flags + b, 1);
}

// ---------------------------------------------------------------- fixup (rare path)
__global__ __launch_bounds__(512) void scan_fix(const float* __restrict__ cur,
                                                const float* __restrict__ decay,
                                                const float* __restrict__ RT,
                                                float* __restrict__ out,
                                                const int* __restrict__ flags) {
  const int b = blockIdx.x;
  if (flags[b] == 0) return;
  const int o = threadIdx.x;
  __shared__ int cnt;
  __shared__ int list[512];
  const float d = decay[o];
  const float om = 1.f - d;
  float v = 0.f, z = 0.f;
  const size_t ci = (size_t)b * 512000 + o;
  const size_t svb = (size_t)b * 512512 + o;
  float* __restrict__ sv = out + SV_OFF;
  float* __restrict__ sz = out + SZ_OFF;
  sv[svb] = 0.f;
  sz[svb] = 0.f;
  if (o == 0) cnt = 0;
  __syncthreads();
  for (int t = 0; t < 1000; ++t) {
    float soma = cur[ci + (size_t)t * 512];
    const int n = cnt;
    for (int i = 0; i < n; ++i) soma += RT[(size_t)list[i] * 512 + o];
    v = d * (v * (1.f - z)) + om * soma;
    z = (v >= 1.0f) ? 1.0f : 0.0f;
    out[ci + (size_t)t * 512] = z;
    sv[svb + (size_t)(t + 1) * 512] = v;
    sz[svb + (size_t)(t + 1) * 512] = z;
    __syncthreads();
    if (o == 0) cnt = 0;
    __syncthreads();
    if (z != 0.f) { const int p = atomicAdd(&cnt, 1); list[p] = o; }
    __syncthreads();
  }
}

extern "C" void kernel_launch(void* const* d_in, const int* in_sizes, int n_in,
                              void* d_out, int out_size, void* d_ws, size_t ws_size,
                              hipStream_t stream) {
  (void)in_sizes; (void)n_in; (void)out_size; (void)ws_size;
  const float* x     = (const float*)d_in[0];  // [64,1000,512]
  const float* W     = (const float*)d_in[1];  // [512,512]
  const float* bias  = (const float*)d_in[2];  // [512]
  const float* R     = (const float*)d_in[3];  // [512,512]
  const float* decay = (const float*)d_in[4];  // [512]
  float* out = (float*)d_out;

  char* ws = (char*)d_ws;
  float* cur          = (float*)ws;                        // 131,072,000 B
  unsigned short* Wb  = (unsigned short*)(ws + 131072000); //     524,288 B
  float* RT           = (float*)(ws + 131596288);          //   1,048,576 B
  int* flags          = (int*)(ws + 132644864);            //       4,096 B
  float* S            = (float*)(ws + 132648960);          //   1,048,576 B
  float* Vs           = (float*)(ws + 133697536);          //   1,048,576 B

  prep<<<1024, 256, 0, stream>>>(W, R, Wb, RT, flags);
  gemm_cur<<<dim3(4, 500), 256, 0, stream>>>(x, Wb, bias, cur);
  chunk_sums<<<1024, 256, 0, stream>>>(cur, decay, S);
  chunk_prefix<<<128, 256, 0, stream>>>(S, decay, Vs);
  chunk_scan<<<1024, 256, 0, stream>>>(cur, decay, Vs, out, flags);
  scan_fix<<<64, 512, 0, stream>>>(cur, decay, RT, out, flags);
}